// Round 8
// baseline (337.758 us; speedup 1.0000x reference)
//
#include <hip/hip_runtime.h>
#include <stdint.h>

// Problem constants
#define S_LEN   1024
#define D_MODEL 4096
#define NHQ     32
#define NKV     8
#define HD      128
#define NTOK    2048   // B*S
#define NQKV    6144   // 4096 q + 1024 k + 1024 v
#define SM_SCALE 0.08838834764831843f

typedef __attribute__((ext_vector_type(8))) __bf16 bf16x8;
typedef __attribute__((ext_vector_type(4))) float f32x4;

__device__ __forceinline__ unsigned short f2bf(float f) {
  union { float f; unsigned u; } x; x.f = f;
  unsigned r = x.u + 0x7fffu + ((x.u >> 16) & 1u);
  return (unsigned short)(r >> 16);
}
__device__ __forceinline__ float bf2f(unsigned short u) {
  union { unsigned u; float f; } x; x.u = (unsigned)u << 16; return x.f;
}

__device__ __forceinline__ void gload_lds16(const void* g, void* l) {
  __builtin_amdgcn_global_load_lds((__attribute__((address_space(1))) void*)g,
                                   (__attribute__((address_space(3))) void*)l,
                                   16, 0, 0);
}

// ---------------- f32 -> bf16 straight conversion (vectorized) ----------------
__global__ void k_f32_to_bf16(const float* __restrict__ in,
                              unsigned short* __restrict__ out, int n8) {
  int i = blockIdx.x * blockDim.x + threadIdx.x;
  if (i >= n8) return;
  const float4* p = (const float4*)(in + (size_t)i * 8);
  float4 v0 = p[0], v1 = p[1];
  uint4 o;
  o.x = f2bf(v0.x) | ((unsigned)f2bf(v0.y) << 16);
  o.y = f2bf(v0.z) | ((unsigned)f2bf(v0.w) << 16);
  o.z = f2bf(v1.x) | ((unsigned)f2bf(v1.y) << 16);
  o.w = f2bf(v1.z) | ((unsigned)f2bf(v1.w) << 16);
  *(uint4*)(out + (size_t)i * 8) = o;
}

// -------- f32 [R][C] -> bf16 [C][R] transpose, 64x64 tiles, vectorized --------
// float4 loads (16B/lane), ushort4 stores (8B/lane, 128B contiguous per
// 16-lane group). LDS [64][65]: read bank = (row+col) mod 32, rows step 4
// across the 16-lane group -> 2 lanes/bank = free.
__global__ __launch_bounds__(256) void k_transpose64(const float* __restrict__ in,
                                                     unsigned short* __restrict__ out,
                                                     int R, int C) {
  __shared__ float t[64][65];
  int rb = blockIdx.y * 64, cb = blockIdx.x * 64;
  int c4 = (threadIdx.x & 15) * 4;
  int r0 = threadIdx.x >> 4;            // 0..15
#pragma unroll
  for (int i = 0; i < 4; ++i) {
    int r = r0 + i * 16;
    float4 v = *(const float4*)&in[(size_t)(rb + r) * C + cb + c4];
    t[r][c4] = v.x; t[r][c4 + 1] = v.y; t[r][c4 + 2] = v.z; t[r][c4 + 3] = v.w;
  }
  __syncthreads();
  int rg = (threadIdx.x & 15) * 4;
  int cc0 = threadIdx.x >> 4;
#pragma unroll
  for (int i = 0; i < 4; ++i) {
    int cc = cc0 + i * 16;
    ushort4 u;
    u.x = f2bf(t[rg][cc]);     u.y = f2bf(t[rg + 1][cc]);
    u.z = f2bf(t[rg + 2][cc]); u.w = f2bf(t[rg + 3][cc]);
    *(ushort4*)&out[(size_t)(cb + cc) * R + rb + rg] = u;
  }
}

// ============ 256 x (NF*64) cross-phase-pipelined bf16 GEMM ===================
// C[M][ldc](OutT) = A[M][K](bf16) * Bt[N][K](bf16)^T ; optional split-K=2:
// blocks [0,nps) compute k-half 0 -> C ; blocks [nps,2nps) k-half 1 -> Cpart
// (deterministic; k_reduce_add sums). MH=2 fixed (proven r4-r6 template).
// 512 thr = 8 waves (2M x 4N), BK=64, dbuf, 4 quadrant-phases/K-tile,
// cross-phase read-ahead (MFMA on prev phase's frags), vmcnt(4) gates at
// q1/q3, never 0. Race audit: r6 (passed). LDS 64-B rows,
// slot^=(row>>1)&3 -> 0 bank conflicts (r2-verified).

#define LGKM0 { asm volatile("s_waitcnt lgkmcnt(0)" ::: "memory"); \
                __builtin_amdgcn_sched_barrier(0); }
#define SCHED __builtin_amdgcn_sched_barrier(0);
#define BAR   __builtin_amdgcn_s_barrier();
#define GATE  asm volatile("s_waitcnt vmcnt(4)" ::: "memory");

#define STGA(h, bufb, kOff)                                                     \
  _Pragma("unroll")                                                             \
  for (int i_ = 0; i_ < 2; ++i_)                                                \
    gload_lds16(gA[i_] + (kOff) + (h) * 64,                                     \
                smem + (bufb) + (h) * 16384 + dA[i_]);

#define STGB(h, bufb, kOff)                                                     \
  _Pragma("unroll")                                                             \
  for (int i_ = 0; i_ < NF / 2; ++i_)                                           \
    gload_lds16(gB[i_] + (kOff) + (h) * 64,                                     \
                smem + (bufb) + 32768 + (h) * (NF * 4096) + dB[i_]);

#define RD_A(dst, mh, kh, bufb)                                                 \
  _Pragma("unroll")                                                             \
  for (int mf = 0; mf < 4; ++mf) {                                              \
    int row = wr * 128 + (mh) * 64 + mf * 16 + lr;                              \
    dst[mf] = *(const bf16x8*)(smem + (bufb) + (kh) * 16384 + row * 64          \
                               + ((lg * 16) ^ (((row >> 1) & 3) << 4)));        \
  }

#define RD_B(dst, kh, bufb)                                                     \
  _Pragma("unroll")                                                             \
  for (int nf = 0; nf < NF; ++nf) {                                             \
    int row = wc * (NF * 16) + nf * 16 + lr;                                    \
    dst[nf] = *(const bf16x8*)(smem + (bufb) + 32768 + (kh) * (NF * 4096)       \
                               + row * 64 + ((lg * 16) ^ (((row >> 1) & 3) << 4))); \
  }

#define MFMA16(mh, AF, BF)                                                      \
  __builtin_amdgcn_s_setprio(1);                                                \
  _Pragma("unroll")                                                             \
  for (int mf = 0; mf < 4; ++mf)                                                \
    _Pragma("unroll")                                                           \
    for (int nf = 0; nf < NF; ++nf)                                             \
      acc[(mh) * 4 + mf][nf] = __builtin_amdgcn_mfma_f32_16x16x32_bf16(         \
          AF[mf], BF[nf], acc[(mh) * 4 + mf][nf], 0, 0, 0);                     \
  __builtin_amdgcn_s_setprio(0);

template <int NF, typename OutT>
__global__ __launch_bounds__(512, 1) void k_gemm256(
    const unsigned short* __restrict__ Aptr,
    const unsigned short* __restrict__ Bptr,
    OutT* __restrict__ C, float* __restrict__ Cpart,
    int Kstride, int ldc, int NT, int SGN, int nxn, int nps) {
  extern __shared__ __align__(16) char smem[];
  constexpr int BUFST = 32768 + NF * 8192;
  int tid = threadIdx.x;
  int l = tid & 63;
  int w = tid >> 6;
  int lr = l & 15, lg = l >> 4;
  int wr = w >> 2, wc = w & 3;
  // split-K id, then XCD 2D supergroup within the split
  int ks = (blockIdx.x >= nps) ? 1 : 0;
  int bid = blockIdx.x - ks * nps;
  int per_xcd = nps >> 3;
  int x8 = bid & 7, i = bid >> 3;
  int SGM = per_xcd / SGN;
  int xr = x8 / nxn, xc = x8 - xr * nxn;
  int iy = i / SGN;
  int by = xr * SGM + iy, bx = xc * SGN + (i - iy * SGN);
  int bm = by * 256, bn = bx * (NF * 64);
  int k0e = ks * NT * 64;

  // hoisted per-thread staging addresses (k0e folded into base)
  const char* gA[2]; int dA[2];
#pragma unroll
  for (int i_ = 0; i_ < 2; ++i_) {
    int lin = i_ * 512 + tid;
    int r_ = lin >> 2, slot = lin & 3, sw = slot ^ ((r_ >> 1) & 3);
    gA[i_] = (const char*)(Aptr + (size_t)(bm + r_) * Kstride + k0e) + sw * 16;
    dA[i_] = lin * 16;
  }
  const char* gB[NF / 2]; int dB[NF / 2];
#pragma unroll
  for (int i_ = 0; i_ < NF / 2; ++i_) {
    int lin = i_ * 512 + tid;
    int r_ = lin >> 2, slot = lin & 3, sw = slot ^ ((r_ >> 1) & 3);
    gB[i_] = (const char*)(Bptr + (size_t)(bn + r_) * Kstride + k0e) + sw * 16;
    dB[i_] = lin * 16;
  }

  f32x4 acc[8][NF] = {};
  bf16x8 afA[4], afB[4], bfA[NF], bfB[NF];

  // prologue: stage K-tile 0 fully into buf0; gate -> h0 complete; publish.
  STGA(0, 0, 0) STGB(0, 0, 0)
  STGA(1, 0, 0) STGB(1, 0, 0)
  GATE
  BAR
  RD_A(afA, 0, 0, 0) RD_B(bfA, 0, 0)

  for (int kt = 0; kt < NT; ++kt) {
    int curb = (kt & 1) * BUFST;
    int nxtb = BUFST - curb;
    int kOff = (kt + 1) * 128;
    // q0 (mh0,kh0): MFMA afA/bfA ; read-ahead af(1,0)
    STGA(0, nxtb, kOff)
    BAR LGKM0
    RD_A(afB, 1, 0, curb) SCHED
    MFMA16(0, afA, bfA)
    BAR
    // q1 (mh1,kh0): read-ahead af(0,1), bf(1)
    STGB(0, nxtb, kOff)
    GATE BAR LGKM0
    RD_A(afA, 0, 1, curb) RD_B(bfB, 1, curb) SCHED
    MFMA16(1, afB, bfA)
    BAR
    // q2 (mh0,kh1): read-ahead af(1,1)
    STGA(1, nxtb, kOff)
    BAR LGKM0
    RD_A(afB, 1, 1, curb) SCHED
    MFMA16(0, afA, bfB)
    BAR
    // q3 (mh1,kh1): read-ahead next-tile (0,0) — after gated barrier
    STGB(1, nxtb, kOff)
    GATE BAR LGKM0
    RD_A(afA, 0, 0, nxtb) RD_B(bfA, 0, nxtb) SCHED
    MFMA16(1, afB, bfB)
    BAR
  }

  // epilogue: C/D layout col=lane&15, row=(lane>>4)*4+j [m89-verified]
#pragma unroll
  for (int mh = 0; mh < 2; ++mh)
#pragma unroll
    for (int mf = 0; mf < 4; ++mf)
#pragma unroll
      for (int nf = 0; nf < NF; ++nf)
#pragma unroll
        for (int j = 0; j < 4; ++j) {
          size_t idx = (size_t)(bm + wr * 128 + mh * 64 + mf * 16 + lg * 4 + j) * ldc +
                       bn + wc * (NF * 16) + nf * 16 + lr;
          float v = acc[mh * 4 + mf][nf][j];
          if (ks) Cpart[idx] = v;
          else if constexpr (sizeof(OutT) == 2) C[idx] = f2bf(v);
          else C[idx] = v;
        }
}

// ---------------- out += partial (vectorized, deterministic) ----------------
__global__ void k_reduce_add(float* __restrict__ out, const float* __restrict__ p,
                             int n4) {
  int i = blockIdx.x * blockDim.x + threadIdx.x;
  int stride = gridDim.x * blockDim.x;
  for (; i < n4; i += stride) {
    float4 a = ((const float4*)out)[i];
    float4 b = ((const float4*)p)[i];
    a.x += b.x; a.y += b.y; a.z += b.z; a.w += b.w;
    ((float4*)out)[i] = a;
  }
}

// ---------------- RMSNorm + RoPE, bf16 qkv -> bf16 head-major ----------------
__global__ void k_norm_rope(const unsigned short* __restrict__ qkv,
                            const float* __restrict__ w,
                            const int* __restrict__ positions,
                            unsigned short* __restrict__ out, int nheads, int colbase,
                            float oscale) {
  int wid = blockIdx.x * 4 + (threadIdx.x >> 6);
  int lane = threadIdx.x & 63;
  int token = wid / nheads, head = wid - token * nheads;
  const unsigned short* src = qkv + (size_t)token * NQKV + colbase + head * HD;
  float e0 = bf2f(src[lane]), e1 = bf2f(src[lane + 64]);
  float ss = e0 * e0 + e1 * e1;
#pragma unroll
  for (int m = 1; m < 64; m <<= 1) ss += __shfl_xor(ss, m, 64);
  float rs = rsqrtf(ss * (1.0f / 128.0f) + 1e-6f);
  float n0 = e0 * rs * w[lane], n1 = e1 * rs * w[lane + 64];
  int pos = positions[token];
  float invf = exp2f((float)lane * (-19.931568569324174f / 64.0f));
  float ang = (float)pos * invf;
  float sv, cv;
  sincosf(ang, &sv, &cv);
  float o0 = (n0 * cv - n1 * sv) * oscale;
  float o1 = (n1 * cv + n0 * sv) * oscale;
  int b = token >> 10, s = token & 1023;
  size_t ob = ((size_t)(b * nheads + head) * S_LEN + s) * HD;
  out[ob + lane] = f2bf(o0);
  out[ob + 64 + lane] = f2bf(o1);
}

// ---------------- V transpose: bf16 qkv v-cols -> bf16 [b][kv][d][s] ----------
__global__ void k_v_transpose(const unsigned short* __restrict__ qkv,
                              unsigned short* __restrict__ vt) {
  __shared__ unsigned short t[32][33];
  int slice = blockIdx.z;              // b*8 + kh
  int b = slice >> 3, kh = slice & 7;
  const unsigned short* in = qkv + (size_t)(b * S_LEN) * NQKV + 5120 + kh * HD;
  unsigned short* out = vt + (size_t)slice * HD * S_LEN;
  int c = threadIdx.x & 31, r0 = threadIdx.x >> 5;
  int s0 = blockIdx.y * 32, d0 = blockIdx.x * 32;
#pragma unroll
  for (int i = 0; i < 4; ++i) {
    int r = r0 + i * 8;
    t[r][c] = in[(size_t)(s0 + r) * NQKV + d0 + c];
  }
  __syncthreads();
#pragma unroll
  for (int i = 0; i < 4; ++i) {
    int r = r0 + i * 8;
    out[(size_t)(d0 + r) * S_LEN + s0 + c] = t[c][r];
  }
}

// ---------------- causal GQA flash attention ----------------
__global__ __launch_bounds__(256) void k_attn(const unsigned short* __restrict__ qh,
                                              const unsigned short* __restrict__ kbuf,
                                              const unsigned short* __restrict__ vtbuf,
                                              unsigned short* __restrict__ attn_out) {
  __shared__ __align__(16) unsigned short k_lds[64 * 128];   // [kv=64][d=128]
  __shared__ __align__(16) unsigned short v_lds[128 * 64];   // [d=128][kv=64]
  __shared__ __align__(16) unsigned short p_lds[4][16 * 64]; // per-wave [q=16][kv=64]
  int b = blockIdx.z, h = blockIdx.y, bx = blockIdx.x;
  int khd = h >> 2;
  int tid = threadIdx.x, w = tid >> 6, l = tid & 63;
  int lr = l & 15, lg = l >> 4;
  const unsigned short* K = kbuf + (size_t)(b * NKV + khd) * S_LEN * HD;
  const unsigned short* VT = vtbuf + (size_t)(b * NKV + khd) * HD * S_LEN;
  char* klp = (char*)k_lds;
  char* vlp = (char*)v_lds;
  char* plp = (char*)p_lds[w];
  int swz = (lr & 7) << 4;

  for (int strip = 0; strip < 2; ++strip) {
    int qs = strip ? (15 - bx) : bx;
    int q0 = qs * 64;
    const unsigned short* Q = qh + ((size_t)(b * NHQ + h) * S_LEN + q0 + w * 16) * HD;
    bf16x8 qf[4];
#pragma unroll
    for (int kk = 0; kk < 4; ++kk)
      qf[kk] = *(const bf16x8*)&Q[(size_t)lr * HD + kk * 32 + lg * 8];

    f32x4 o[8] = {};
    float m_[4], l_[4];
#pragma unroll
    for (int j = 0; j < 4; ++j) { m_[j] = -1e30f; l_[j] = 0.0f; }

    int nt = qs + 1;
    for (int t = 0; t < nt; ++t) {
      int t0 = t * 64;
      __syncthreads();
#pragma unroll
      for (int it = 0; it < 4; ++it) {
        int db = (tid + it * 256) * 16;
        int kr = db >> 8, kc = db & 255;
        gload_lds16(K + (size_t)(t0 + kr) * HD + ((kc ^ ((kr & 7) << 4)) >> 1), klp + db);
        int vr = db >> 7, vc = db & 127;
        gload_lds16(VT + (size_t)vr * S_LEN + t0 + ((vc ^ ((vr & 7) << 4)) >> 1), vlp + db);
      }
      __syncthreads();

      f32x4 sc[4];
      __builtin_amdgcn_s_setprio(1);
#pragma unroll
      for (int ct = 0; ct < 4; ++ct) {
        f32x4 s = {};
        int row = ct * 16 + lr;
#pragma unroll
        for (int kk = 0; kk < 4; ++kk) {
          bf16x8 kf = *(const bf16x8*)(klp + row * 256 + ((kk * 64 + lg * 16) ^ swz));
          s = __builtin_amdgcn_mfma_f32_16x16x32_bf16(qf[kk], kf, s, 0, 0, 0);
        }
        sc[ct] = s;
      }
      __builtin_amdgcn_s_setprio(0);

      bool full = (t < qs);
      float alpha[4];
#pragma unroll
      for (int j = 0; j < 4; ++j) {
        if (!full) {
          int rg = q0 + w * 16 + lg * 4 + j;
#pragma unroll
          for (int ct = 0; ct < 4; ++ct)
            sc[ct][j] = (t0 + ct * 16 + lr <= rg) ? sc[ct][j] : -1e30f;
        }
        float mx = fmaxf(fmaxf(sc[0][j], sc[1][j]), fmaxf(sc[2][j], sc[3][j]));
#pragma unroll
        for (int msk = 1; msk < 16; msk <<= 1) mx = fmaxf(mx, __shfl_xor(mx, msk, 64));
        float mn = fmaxf(m_[j], mx);
        alpha[j] = __expf(m_[j] - mn);
        int q = lg * 4 + j;
        int psw = (q & 7) << 4;
        float ps = 0.0f;
#pragma unroll
        for (int ct = 0; ct < 4; ++ct) {
          float p = __expf(sc[ct][j] - mn);
          ps += p;
          *(unsigned short*)(plp + q * 128 + (((ct * 16 + lr) * 2) ^ psw)) = f2bf(p);
        }
#pragma unroll
        for (int msk = 1; msk < 16; msk <<= 1) ps += __shfl_xor(ps, msk, 64);
        l_[j] = l_[j] * alpha[j] + ps;
        m_[j] = mn;
      }
#pragma unroll
      for (int dc = 0; dc < 8; ++dc) {
        o[dc][0] *= alpha[0]; o[dc][1] *= alpha[1];
        o[dc][2] *= alpha[2]; o[dc][3] *= alpha[3];
      }
      asm volatile("s_waitcnt lgkmcnt(0)" ::: "memory");
      __builtin_amdgcn_s_setprio(1);
#pragma unroll
      for (int kt = 0; kt < 2; ++kt) {
        bf16x8 pa = *(const bf16x8*)(plp + lr * 128 + ((kt * 64 + lg * 16) ^ swz));
#pragma unroll
        for (int dc = 0; dc < 8; ++dc) {
          int vrow = dc * 16 + lr;
          bf16x8 vf = *(const bf16x8*)(vlp + vrow * 128 + ((kt * 64 + lg * 16) ^ swz));
          o[dc] = __builtin_amdgcn_mfma_f32_16x16x32_bf16(pa, vf, o[dc], 0, 0, 0);
        }
      }
      __builtin_amdgcn_s_setprio(0);
    }

#pragma unroll
    for (int j = 0; j < 4; ++j) {
      int rg = q0 + w * 16 + lg * 4 + j;
      size_t row = (size_t)(b * S_LEN + rg) * D_MODEL + h * HD;
      float inv = 1.0f / l_[j];
#pragma unroll
      for (int dc = 0; dc < 8; ++dc)
        attn_out[row + dc * 16 + lr] = f2bf(o[dc][j] * inv);
    }
  }
}

extern "C" void kernel_launch(void* const* d_in, const int* in_sizes, int n_in,
                              void* d_out, int out_size, void* d_ws, size_t ws_size,
                              hipStream_t stream) {
  const float* x        = (const float*)d_in[0];
  const int* positions  = (const int*)d_in[1];
  const float* wq       = (const float*)d_in[2];
  const float* wk       = (const float*)d_in[3];
  const float* wv       = (const float*)d_in[4];
  const float* wo       = (const float*)d_in[5];
  const float* qnw      = (const float*)d_in[6];
  const float* knw      = (const float*)d_in[7];
  float* out            = (float*)d_out;

  // workspace layout (126 MB used, lifetime-based reuse)
  char* ws = (char*)d_ws;
  unsigned short* xb   = (unsigned short*)(ws);                    // 16.78 MB [x bf16] -> attn_out
  unsigned short* wB   = (unsigned short*)(ws + 16777216);         // 50.33 MB [qkv wT] -> q/k/vt -> gemm2 partial
  unsigned short* woT  = (unsigned short*)(ws + 67108864);         // 33.55 MB [wo bf16 T]
  unsigned short* qkvb = (unsigned short*)(ws + 100663296);        // 25.17 MB [qkv bf16]
  unsigned short* qh   = wB;                                        // 16.78 MB
  unsigned short* khb  = (unsigned short*)(ws + 33554432);          //  4.19 MB
  unsigned short* vtb  = (unsigned short*)(ws + 37748736);          //  4.19 MB
  unsigned short* attn = xb;                                        // 16.78 MB
  float*          part = (float*)(ws + 16777216);                   // 33.55 MB (qh/khb/vtb dead by GEMM2)

  dim3 tb(256);
  k_f32_to_bf16<<<4096, tb, 0, stream>>>(x, xb, 1048576);
  k_transpose64<<<dim3(64, 64), tb, 0, stream>>>(wq, wB, 4096, 4096);
  k_transpose64<<<dim3(16, 64), tb, 0, stream>>>(wk, wB + (size_t)4096 * 4096, 4096, 1024);
  k_transpose64<<<dim3(16, 64), tb, 0, stream>>>(wv, wB + (size_t)5120 * 4096, 4096, 1024);
  k_transpose64<<<dim3(64, 64), tb, 0, stream>>>(wo, woT, 4096, 4096);

  // GEMM1: [2048][4096] x [6144][4096]^T -> qkv bf16; grid 192 = 8 XCD x (4x6)
  k_gemm256<4, unsigned short><<<dim3(192), dim3(512), 131072, stream>>>(
      xb, wB, qkvb, nullptr, 4096, 6144, 64, 6, 4, 192);

  k_norm_rope<<<16384, tb, 0, stream>>>(qkvb, qnw, positions, qh, 32, 0, SM_SCALE);
  k_norm_rope<<<4096, tb, 0, stream>>>(qkvb, knw, positions, khb, 8, 4096, 1.0f);
  k_v_transpose<<<dim3(4, 32, 16), tb, 0, stream>>>(qkvb, vtb);

  k_attn<<<dim3(8, 32, 2), tb, 0, stream>>>(qh, khb, vtb, attn);

  // GEMM2: [2048][4096] x [4096][4096]^T, split-K=2 deterministic:
  // blocks 0-127 (K 0:2048) -> out ; blocks 128-255 (K 2048:4096) -> part
  // per-split grid 128 = 8 XCD x (4x4); then out += part.
  k_gemm256<4, float><<<dim3(256), dim3(512), 131072, stream>>>(
      attn, woT, out, part, 4096, 4096, 32, 4, 4, 128);
  k_reduce_add<<<2048, tb, 0, stream>>>(out, part, 2097152);
}

// Round 9
// 325.459 us; speedup vs baseline: 1.0378x; 1.0378x over previous
//
#include <hip/hip_runtime.h>
#include <stdint.h>

// Problem constants
#define S_LEN   1024
#define D_MODEL 4096
#define NHQ     32
#define NKV     8
#define HD      128
#define NTOK    2048   // B*S
#define NQKV    6144   // 4096 q + 1024 k + 1024 v
#define SM_SCALE 0.08838834764831843f

typedef __attribute__((ext_vector_type(8))) __bf16 bf16x8;
typedef __attribute__((ext_vector_type(4))) float f32x4;

__device__ __forceinline__ unsigned short f2bf(float f) {
  union { float f; unsigned u; } x; x.f = f;
  unsigned r = x.u + 0x7fffu + ((x.u >> 16) & 1u);
  return (unsigned short)(r >> 16);
}
__device__ __forceinline__ float bf2f(unsigned short u) {
  union { unsigned u; float f; } x; x.u = (unsigned)u << 16; return x.f;
}

__device__ __forceinline__ void gload_lds16(const void* g, void* l) {
  __builtin_amdgcn_global_load_lds((__attribute__((address_space(1))) void*)g,
                                   (__attribute__((address_space(3))) void*)l,
                                   16, 0, 0);
}

// ---------------- f32 -> bf16 straight conversion (vectorized) ----------------
__global__ void k_f32_to_bf16(const float* __restrict__ in,
                              unsigned short* __restrict__ out, int n8) {
  int i = blockIdx.x * blockDim.x + threadIdx.x;
  if (i >= n8) return;
  const float4* p = (const float4*)(in + (size_t)i * 8);
  float4 v0 = p[0], v1 = p[1];
  uint4 o;
  o.x = f2bf(v0.x) | ((unsigned)f2bf(v0.y) << 16);
  o.y = f2bf(v0.z) | ((unsigned)f2bf(v0.w) << 16);
  o.z = f2bf(v1.x) | ((unsigned)f2bf(v1.y) << 16);
  o.w = f2bf(v1.z) | ((unsigned)f2bf(v1.w) << 16);
  *(uint4*)(out + (size_t)i * 8) = o;
}

// ---------------- f32 [R][C] -> bf16 [C][R] tiled transpose (r6-proven) -------
__global__ void k_transpose(const float* __restrict__ in,
                            unsigned short* __restrict__ out, int R, int C) {
  __shared__ float t[32][33];
  int c = threadIdx.x & 31, r0 = threadIdx.x >> 5;   // 256 threads: 8 rows x 32 cols
  int cb = blockIdx.x * 32, rb = blockIdx.y * 32;
#pragma unroll
  for (int i = 0; i < 4; ++i) {
    int r = r0 + i * 8;
    t[r][c] = in[(size_t)(rb + r) * C + cb + c];
  }
  __syncthreads();
#pragma unroll
  for (int i = 0; i < 4; ++i) {
    int r = r0 + i * 8;
    out[(size_t)(cb + r) * R + rb + c] = f2bf(t[c][r]);
  }
}

// ============ 256 x (NF*64) cross-phase-pipelined bf16 GEMM ===================
// C[M][ldc](OutT) = A[M][K](bf16) * Bt[N][K](bf16)^T
// MH=2 fixed (BM=256); NF = B-frags/wave: NF=4 -> BN=256, NF=2 -> BN=128.
// 512 thr = 8 waves (2M x 4N), BK=64, dbuf, 4 quadrant-phases/K-tile,
// cross-phase read-ahead (MFMA on prev phase's frags), counted vmcnt gates at
// q1/q3 only (never 0). Per-tile per-thread loads: 2,NF/2,2,NF/2 ->
// gate = vmcnt(2+NF/2) forces exactly the two prior half-tile stages
// (audit r4/r6-verified for NF=4; NF=2 re-derived this round).
// LDS rows 64B, slot-swizzle slot^=(row>>1)&3 -> 0 bank conflicts (r2-verified).

#define LGKM0 { asm volatile("s_waitcnt lgkmcnt(0)" ::: "memory"); \
                __builtin_amdgcn_sched_barrier(0); }
#define SCHED __builtin_amdgcn_sched_barrier(0);
#define BAR   __builtin_amdgcn_s_barrier();
#define GATE  { if constexpr (NF == 4)                                          \
                  asm volatile("s_waitcnt vmcnt(4)" ::: "memory");              \
                else                                                            \
                  asm volatile("s_waitcnt vmcnt(3)" ::: "memory"); }

#define STGA(h, bufb, kOff)                                                     \
  _Pragma("unroll")                                                             \
  for (int i_ = 0; i_ < 2; ++i_)                                                \
    gload_lds16(gA[i_] + (kOff) + (h) * 64,                                     \
                smem + (bufb) + (h) * 16384 + dA[i_]);

#define STGB(h, bufb, kOff)                                                     \
  _Pragma("unroll")                                                             \
  for (int i_ = 0; i_ < NF / 2; ++i_)                                           \
    gload_lds16(gB[i_] + (kOff) + (h) * 64,                                     \
                smem + (bufb) + 32768 + (h) * (NF * 4096) + dB[i_]);

#define RD_A(dst, mh, kh, bufb)                                                 \
  _Pragma("unroll")                                                             \
  for (int mf = 0; mf < 4; ++mf) {                                              \
    int row = wr * 128 + (mh) * 64 + mf * 16 + lr;                              \
    dst[mf] = *(const bf16x8*)(smem + (bufb) + (kh) * 16384 + row * 64          \
                               + ((lg * 16) ^ (((row >> 1) & 3) << 4)));        \
  }

#define RD_B(dst, kh, bufb)                                                     \
  _Pragma("unroll")                                                             \
  for (int nf = 0; nf < NF; ++nf) {                                             \
    int row = wc * (NF * 16) + nf * 16 + lr;                                    \
    dst[nf] = *(const bf16x8*)(smem + (bufb) + 32768 + (kh) * (NF * 4096)       \
                               + row * 64 + ((lg * 16) ^ (((row >> 1) & 3) << 4))); \
  }

#define MFMA16(mh, AF, BF)                                                      \
  __builtin_amdgcn_s_setprio(1);                                                \
  _Pragma("unroll")                                                             \
  for (int mf = 0; mf < 4; ++mf)                                                \
    _Pragma("unroll")                                                           \
    for (int nf = 0; nf < NF; ++nf)                                             \
      acc[(mh) * 4 + mf][nf] = __builtin_amdgcn_mfma_f32_16x16x32_bf16(         \
          AF[mf], BF[nf], acc[(mh) * 4 + mf][nf], 0, 0, 0);                     \
  __builtin_amdgcn_s_setprio(0);

template <int NF, typename OutT>
__global__ __launch_bounds__(512, 1) void k_gemm256(
    const unsigned short* __restrict__ Aptr,
    const unsigned short* __restrict__ Bptr,
    OutT* __restrict__ C,
    int Kstride, int ldc, int NT, int SGN, int nxn) {
  extern __shared__ __align__(16) char smem[];
  constexpr int BUFST = 32768 + NF * 8192;
  int tid = threadIdx.x;
  int l = tid & 63;
  int w = tid >> 6;
  int lr = l & 15, lg = l >> 4;
  int wr = w >> 2, wc = w & 3;
  // XCD 2D supergroup: XCD x8 owns a SGM x SGN block sub-grid
  int per_xcd = gridDim.x >> 3;
  int x8 = blockIdx.x & 7, i = blockIdx.x >> 3;
  int SGM = per_xcd / SGN;
  int xr = x8 / nxn, xc = x8 - xr * nxn;
  int iy = i / SGN;
  int by = xr * SGM + iy, bx = xc * SGN + (i - iy * SGN);
  int bm = by * 256, bn = bx * (NF * 64);

  // hoisted per-thread staging addresses
  const char* gA[2]; int dA[2];
#pragma unroll
  for (int i_ = 0; i_ < 2; ++i_) {
    int lin = i_ * 512 + tid;
    int r_ = lin >> 2, slot = lin & 3, sw = slot ^ ((r_ >> 1) & 3);
    gA[i_] = (const char*)(Aptr + (size_t)(bm + r_) * Kstride) + sw * 16;
    dA[i_] = lin * 16;
  }
  const char* gB[NF / 2]; int dB[NF / 2];
#pragma unroll
  for (int i_ = 0; i_ < NF / 2; ++i_) {
    int lin = i_ * 512 + tid;
    int r_ = lin >> 2, slot = lin & 3, sw = slot ^ ((r_ >> 1) & 3);
    gB[i_] = (const char*)(Bptr + (size_t)(bn + r_) * Kstride) + sw * 16;
    dB[i_] = lin * 16;
  }

  f32x4 acc[8][NF] = {};
  bf16x8 afA[4], afB[4], bfA[NF], bfB[NF];

  // prologue: stage K-tile 0 fully into buf0; gate -> h0 complete; publish.
  STGA(0, 0, 0) STGB(0, 0, 0)
  STGA(1, 0, 0) STGB(1, 0, 0)
  GATE
  BAR
  RD_A(afA, 0, 0, 0) RD_B(bfA, 0, 0)

  for (int kt = 0; kt < NT; ++kt) {
    int curb = (kt & 1) * BUFST;
    int nxtb = BUFST - curb;
    int kOff = (kt + 1) * 128;
    // q0 (mh0,kh0): MFMA afA/bfA ; read-ahead af(1,0)
    STGA(0, nxtb, kOff)
    BAR LGKM0
    RD_A(afB, 1, 0, curb) SCHED
    MFMA16(0, afA, bfA)
    BAR
    // q1 (mh1,kh0): read-ahead af(0,1), bf(1)
    STGB(0, nxtb, kOff)
    GATE BAR LGKM0
    RD_A(afA, 0, 1, curb) RD_B(bfB, 1, curb) SCHED
    MFMA16(1, afB, bfA)
    BAR
    // q2 (mh0,kh1): read-ahead af(1,1)
    STGA(1, nxtb, kOff)
    BAR LGKM0
    RD_A(afB, 1, 1, curb) SCHED
    MFMA16(0, afA, bfB)
    BAR
    // q3 (mh1,kh1): read-ahead next-tile (0,0) — after gated barrier
    STGB(1, nxtb, kOff)
    GATE BAR LGKM0
    RD_A(afA, 0, 0, nxtb) RD_B(bfA, 0, nxtb) SCHED
    MFMA16(1, afB, bfB)
    BAR
  }

  // epilogue: C/D layout col=lane&15, row=(lane>>4)*4+j [m89-verified]
#pragma unroll
  for (int mh = 0; mh < 2; ++mh)
#pragma unroll
    for (int mf = 0; mf < 4; ++mf)
#pragma unroll
      for (int nf = 0; nf < NF; ++nf)
#pragma unroll
        for (int j = 0; j < 4; ++j) {
          size_t idx = (size_t)(bm + wr * 128 + mh * 64 + mf * 16 + lg * 4 + j) * ldc +
                       bn + wc * (NF * 16) + nf * 16 + lr;
          float v = acc[mh * 4 + mf][nf][j];
          if constexpr (sizeof(OutT) == 2) C[idx] = f2bf(v);
          else C[idx] = v;
        }
}

// ---------------- RMSNorm + RoPE, bf16 qkv -> bf16 head-major ----------------
__global__ void k_norm_rope(const unsigned short* __restrict__ qkv,
                            const float* __restrict__ w,
                            const int* __restrict__ positions,
                            unsigned short* __restrict__ out, int nheads, int colbase,
                            float oscale) {
  int wid = blockIdx.x * 4 + (threadIdx.x >> 6);
  int lane = threadIdx.x & 63;
  int token = wid / nheads, head = wid - token * nheads;
  const unsigned short* src = qkv + (size_t)token * NQKV + colbase + head * HD;
  float e0 = bf2f(src[lane]), e1 = bf2f(src[lane + 64]);
  float ss = e0 * e0 + e1 * e1;
#pragma unroll
  for (int m = 1; m < 64; m <<= 1) ss += __shfl_xor(ss, m, 64);
  float rs = rsqrtf(ss * (1.0f / 128.0f) + 1e-6f);
  float n0 = e0 * rs * w[lane], n1 = e1 * rs * w[lane + 64];
  int pos = positions[token];
  float invf = exp2f((float)lane * (-19.931568569324174f / 64.0f));
  float ang = (float)pos * invf;
  float sv, cv;
  sincosf(ang, &sv, &cv);
  float o0 = (n0 * cv - n1 * sv) * oscale;
  float o1 = (n1 * cv + n0 * sv) * oscale;
  int b = token >> 10, s = token & 1023;
  size_t ob = ((size_t)(b * nheads + head) * S_LEN + s) * HD;
  out[ob + lane] = f2bf(o0);
  out[ob + 64 + lane] = f2bf(o1);
}

// ---------------- V transpose: bf16 qkv v-cols -> bf16 [b][kv][d][s] ----------
__global__ void k_v_transpose(const unsigned short* __restrict__ qkv,
                              unsigned short* __restrict__ vt) {
  __shared__ unsigned short t[32][33];
  int slice = blockIdx.z;              // b*8 + kh
  int b = slice >> 3, kh = slice & 7;
  const unsigned short* in = qkv + (size_t)(b * S_LEN) * NQKV + 5120 + kh * HD;
  unsigned short* out = vt + (size_t)slice * HD * S_LEN;
  int c = threadIdx.x & 31, r0 = threadIdx.x >> 5;
  int s0 = blockIdx.y * 32, d0 = blockIdx.x * 32;
#pragma unroll
  for (int i = 0; i < 4; ++i) {
    int r = r0 + i * 8;
    t[r][c] = in[(size_t)(s0 + r) * NQKV + d0 + c];
  }
  __syncthreads();
#pragma unroll
  for (int i = 0; i < 4; ++i) {
    int r = r0 + i * 8;
    out[(size_t)(d0 + r) * S_LEN + s0 + c] = t[c][r];
  }
}

// ---------------- causal GQA flash attention ----------------
__global__ __launch_bounds__(256) void k_attn(const unsigned short* __restrict__ qh,
                                              const unsigned short* __restrict__ kbuf,
                                              const unsigned short* __restrict__ vtbuf,
                                              unsigned short* __restrict__ attn_out) {
  __shared__ __align__(16) unsigned short k_lds[64 * 128];   // [kv=64][d=128]
  __shared__ __align__(16) unsigned short v_lds[128 * 64];   // [d=128][kv=64]
  __shared__ __align__(16) unsigned short p_lds[4][16 * 64]; // per-wave [q=16][kv=64]
  int b = blockIdx.z, h = blockIdx.y, bx = blockIdx.x;
  int khd = h >> 2;
  int tid = threadIdx.x, w = tid >> 6, l = tid & 63;
  int lr = l & 15, lg = l >> 4;
  const unsigned short* K = kbuf + (size_t)(b * NKV + khd) * S_LEN * HD;
  const unsigned short* VT = vtbuf + (size_t)(b * NKV + khd) * HD * S_LEN;
  char* klp = (char*)k_lds;
  char* vlp = (char*)v_lds;
  char* plp = (char*)p_lds[w];
  int swz = (lr & 7) << 4;

  for (int strip = 0; strip < 2; ++strip) {
    int qs = strip ? (15 - bx) : bx;
    int q0 = qs * 64;
    const unsigned short* Q = qh + ((size_t)(b * NHQ + h) * S_LEN + q0 + w * 16) * HD;
    bf16x8 qf[4];
#pragma unroll
    for (int kk = 0; kk < 4; ++kk)
      qf[kk] = *(const bf16x8*)&Q[(size_t)lr * HD + kk * 32 + lg * 8];

    f32x4 o[8] = {};
    float m_[4], l_[4];
#pragma unroll
    for (int j = 0; j < 4; ++j) { m_[j] = -1e30f; l_[j] = 0.0f; }

    int nt = qs + 1;
    for (int t = 0; t < nt; ++t) {
      int t0 = t * 64;
      __syncthreads();
#pragma unroll
      for (int it = 0; it < 4; ++it) {
        int db = (tid + it * 256) * 16;
        int kr = db >> 8, kc = db & 255;
        gload_lds16(K + (size_t)(t0 + kr) * HD + ((kc ^ ((kr & 7) << 4)) >> 1), klp + db);
        int vr = db >> 7, vc = db & 127;
        gload_lds16(VT + (size_t)vr * S_LEN + t0 + ((vc ^ ((vr & 7) << 4)) >> 1), vlp + db);
      }
      __syncthreads();

      f32x4 sc[4];
      __builtin_amdgcn_s_setprio(1);
#pragma unroll
      for (int ct = 0; ct < 4; ++ct) {
        f32x4 s = {};
        int row = ct * 16 + lr;
#pragma unroll
        for (int kk = 0; kk < 4; ++kk) {
          bf16x8 kf = *(const bf16x8*)(klp + row * 256 + ((kk * 64 + lg * 16) ^ swz));
          s = __builtin_amdgcn_mfma_f32_16x16x32_bf16(qf[kk], kf, s, 0, 0, 0);
        }
        sc[ct] = s;
      }
      __builtin_amdgcn_s_setprio(0);

      bool full = (t < qs);
      float alpha[4];
#pragma unroll
      for (int j = 0; j < 4; ++j) {
        if (!full) {
          int rg = q0 + w * 16 + lg * 4 + j;
#pragma unroll
          for (int ct = 0; ct < 4; ++ct)
            sc[ct][j] = (t0 + ct * 16 + lr <= rg) ? sc[ct][j] : -1e30f;
        }
        float mx = fmaxf(fmaxf(sc[0][j], sc[1][j]), fmaxf(sc[2][j], sc[3][j]));
#pragma unroll
        for (int msk = 1; msk < 16; msk <<= 1) mx = fmaxf(mx, __shfl_xor(mx, msk, 64));
        float mn = fmaxf(m_[j], mx);
        alpha[j] = __expf(m_[j] - mn);
        int q = lg * 4 + j;
        int psw = (q & 7) << 4;
        float ps = 0.0f;
#pragma unroll
        for (int ct = 0; ct < 4; ++ct) {
          float p = __expf(sc[ct][j] - mn);
          ps += p;
          *(unsigned short*)(plp + q * 128 + (((ct * 16 + lr) * 2) ^ psw)) = f2bf(p);
        }
#pragma unroll
        for (int msk = 1; msk < 16; msk <<= 1) ps += __shfl_xor(ps, msk, 64);
        l_[j] = l_[j] * alpha[j] + ps;
        m_[j] = mn;
      }
#pragma unroll
      for (int dc = 0; dc < 8; ++dc) {
        o[dc][0] *= alpha[0]; o[dc][1] *= alpha[1];
        o[dc][2] *= alpha[2]; o[dc][3] *= alpha[3];
      }
      asm volatile("s_waitcnt lgkmcnt(0)" ::: "memory");
      __builtin_amdgcn_s_setprio(1);
#pragma unroll
      for (int kt = 0; kt < 2; ++kt) {
        bf16x8 pa = *(const bf16x8*)(plp + lr * 128 + ((kt * 64 + lg * 16) ^ swz));
#pragma unroll
        for (int dc = 0; dc < 8; ++dc) {
          int vrow = dc * 16 + lr;
          bf16x8 vf = *(const bf16x8*)(vlp + vrow * 128 + ((kt * 64 + lg * 16) ^ swz));
          o[dc] = __builtin_amdgcn_mfma_f32_16x16x32_bf16(pa, vf, o[dc], 0, 0, 0);
        }
      }
      __builtin_amdgcn_s_setprio(0);
    }

#pragma unroll
    for (int j = 0; j < 4; ++j) {
      int rg = q0 + w * 16 + lg * 4 + j;
      size_t row = (size_t)(b * S_LEN + rg) * D_MODEL + h * HD;
      float inv = 1.0f / l_[j];
#pragma unroll
      for (int dc = 0; dc < 8; ++dc)
        attn_out[row + dc * 16 + lr] = f2bf(o[dc][j] * inv);
    }
  }
}

extern "C" void kernel_launch(void* const* d_in, const int* in_sizes, int n_in,
                              void* d_out, int out_size, void* d_ws, size_t ws_size,
                              hipStream_t stream) {
  const float* x        = (const float*)d_in[0];
  const int* positions  = (const int*)d_in[1];
  const float* wq       = (const float*)d_in[2];
  const float* wk       = (const float*)d_in[3];
  const float* wv       = (const float*)d_in[4];
  const float* wo       = (const float*)d_in[5];
  const float* qnw      = (const float*)d_in[6];
  const float* knw      = (const float*)d_in[7];
  float* out            = (float*)d_out;

  // workspace layout (126 MB used, lifetime-based reuse)
  char* ws = (char*)d_ws;
  unsigned short* xb   = (unsigned short*)(ws);                    // 16.78 MB [x bf16] -> attn_out
  unsigned short* wB   = (unsigned short*)(ws + 16777216);         // 50.33 MB [qkv wT] -> q/k/vt
  unsigned short* woT  = (unsigned short*)(ws + 67108864);         // 33.55 MB [wo bf16 T]
  unsigned short* qkvb = (unsigned short*)(ws + 100663296);        // 25.17 MB [qkv bf16]
  unsigned short* qh   = wB;                                        // 16.78 MB
  unsigned short* khb  = (unsigned short*)(ws + 33554432);          //  4.19 MB
  unsigned short* vtb  = (unsigned short*)(ws + 37748736);          //  4.19 MB
  unsigned short* attn = xb;                                        // 16.78 MB

  dim3 tb(256);
  k_f32_to_bf16<<<4096, tb, 0, stream>>>(x, xb, 1048576);
  k_transpose<<<dim3(128, 128), tb, 0, stream>>>(wq, wB, 4096, 4096);
  k_transpose<<<dim3(32, 128), tb, 0, stream>>>(wk, wB + (size_t)4096 * 4096, 4096, 1024);
  k_transpose<<<dim3(32, 128), tb, 0, stream>>>(wv, wB + (size_t)5120 * 4096, 4096, 1024);
  k_transpose<<<dim3(128, 128), tb, 0, stream>>>(wo, woT, 4096, 4096);

  // GEMM1: [2048][4096] x [6144][4096]^T -> qkv bf16, BM=256/BN=256
  // grid 192 = 8 XCD x (4bm x 6bn); smem 128 KiB
  k_gemm256<4, unsigned short><<<dim3(192), dim3(512), 131072, stream>>>(
      xb, wB, qkvb, 4096, 6144, 64, 6, 4);

  k_norm_rope<<<16384, tb, 0, stream>>>(qkvb, qnw, positions, qh, 32, 0, SM_SCALE);
  k_norm_rope<<<4096, tb, 0, stream>>>(qkvb, knw, positions, khb, 8, 4096, 1.0f);
  k_v_transpose<<<dim3(4, 32, 16), tb, 0, stream>>>(qkvb, vtb);

  k_attn<<<dim3(8, 32, 2), tb, 0, stream>>>(qh, khb, vtb, attn);

  // GEMM2: [2048][4096] x [4096][4096]^T -> out f32, BM=256/BN=128
  // grid 256 = full chip = 8 XCD x (4bm x 8bn); smem 96 KiB; no split-K
  k_gemm256<2, float><<<dim3(256), dim3(512), 98304, stream>>>(
      attn, woT, out, 4096, 4096, 64, 8, 4);
}